// Round 1
// baseline (39.063 us; speedup 1.0000x reference)
//
#include <hip/hip_runtime.h>
#include <math.h>

#define DIM     1024
#define NSTAGES 10
#define HALFD   512                   // angles per stage = DIM/2
#define TABN    (NSTAGES * HALFD)     // 5120 floats per table

// ---------------------------------------------------------------------------
// Prep: cos/sin tables into workspace. ws layout: cos[10][512] | sin[10][512]
// ---------------------------------------------------------------------------
__global__ void bf_prep(const float* __restrict__ ang, float* __restrict__ ws) {
    int i = blockIdx.x * blockDim.x + threadIdx.x;
    if (i < TABN) {
        float s, c;
        sincosf(ang[i], &s, &c);
        ws[i]        = c;
        ws[TABN + i] = s;
    }
}

// ---------------------------------------------------------------------------
// Main fused butterfly. Lane layout: lane owns elements e = 256*c + 4*lane + d
// (c=0..3 register groups, d=0..3 within float4).
//   stage 0,1  : intra-float4
//   stage 2..7 : cross-lane, shfl_xor mask m = 1<<(s-2)  (1..32)
//   stage 8,9  : intra-lane across c-groups
// Angles: stage s pair with left element i has index
//   p = ((i >> (s+1)) << s) | (i & (half-1)),  half = 1<<s
// ---------------------------------------------------------------------------
template <int USE_TAB>
__global__ __launch_bounds__(256) void bf_main(
    const float* __restrict__ x,
    const float* __restrict__ ang,
    const float* __restrict__ tab,
    float* __restrict__ out,
    int nrows)
{
    __shared__ __align__(16) float cosT[TABN];
    __shared__ __align__(16) float sinT[TABN];
    const int tid = threadIdx.x;

    if (USE_TAB) {
        const float4* s4 = (const float4*)tab;
        float4* c4 = (float4*)cosT;
        float4* n4 = (float4*)sinT;
        #pragma unroll
        for (int i = 0; i < TABN / 4 / 256; ++i) {   // 5 iterations
            int idx = i * 256 + tid;
            c4[idx] = s4[idx];
            n4[idx] = s4[TABN / 4 + idx];
        }
    } else {
        for (int i = tid; i < TABN; i += 256) {
            float s, c;
            sincosf(ang[i], &s, &c);
            cosT[i] = c;
            sinT[i] = s;
        }
    }
    __syncthreads();

    const int lane = tid & 63;
    const int wid  = blockIdx.x * (256 / 64) + (tid >> 6);
    const int R = 2;
    const int row0 = wid * R;
    if (row0 >= nrows) return;

    // ---- load: perfectly coalesced, lane reads float4 at byte 16*lane -----
    float4 v[R][4];
    #pragma unroll
    for (int r = 0; r < R; ++r) {
        const float4* xp = ((const float4*)(x + (size_t)(row0 + r) * DIM)) + lane;
        #pragma unroll
        for (int c = 0; c < 4; ++c)
            v[r][c] = xp[64 * c];
    }

    // ---- stages 0,1: intra-float4. Angle idx p = 128c + 2*lane + {0,1} ----
    #pragma unroll
    for (int s01 = 0; s01 < 2; ++s01) {
        const float* cT = cosT + s01 * HALFD;
        const float* sT = sinT + s01 * HALFD;
        #pragma unroll
        for (int c = 0; c < 4; ++c) {
            const int p = 128 * c + 2 * lane;
            float2 cc = *(const float2*)&cT[p];
            float2 ss = *(const float2*)&sT[p];
            #pragma unroll
            for (int r = 0; r < R; ++r) {
                float4 u = v[r][c];
                if (s01 == 0) {
                    // pairs (x,y) and (z,w)
                    v[r][c].x = cc.x * u.x + ss.x * u.y;
                    v[r][c].y = cc.x * u.y - ss.x * u.x;
                    v[r][c].z = cc.y * u.z + ss.y * u.w;
                    v[r][c].w = cc.y * u.w - ss.y * u.z;
                } else {
                    // pairs (x,z) and (y,w)
                    v[r][c].x = cc.x * u.x + ss.x * u.z;
                    v[r][c].z = cc.x * u.z - ss.x * u.x;
                    v[r][c].y = cc.y * u.y + ss.y * u.w;
                    v[r][c].w = cc.y * u.w - ss.y * u.y;
                }
            }
        }
    }

    // ---- stages 2..7: cross-lane via shfl_xor -----------------------------
    #pragma unroll
    for (int s = 2; s <= 7; ++s) {
        const int m = 1 << (s - 2);
        const float* cT = cosT + s * HALFD;
        const float* sT = sinT + s * HALFD;
        const int l0 = lane & ~m;                  // left lane of the pair
        const float sgn = (lane & m) ? -1.0f : 1.0f;
        #pragma unroll
        for (int c = 0; c < 4; ++c) {
            const int p0 = (((c << (7 - s)) + (l0 >> (s - 1))) << s)
                         + 4 * (l0 & (m - 1));
            float4 C = *(const float4*)&cT[p0];
            float4 S = *(const float4*)&sT[p0];
            S.x *= sgn; S.y *= sgn; S.z *= sgn; S.w *= sgn;
            #pragma unroll
            for (int r = 0; r < R; ++r) {
                float4 u = v[r][c];
                float tx = __shfl_xor(u.x, m, 64);
                float ty = __shfl_xor(u.y, m, 64);
                float tz = __shfl_xor(u.z, m, 64);
                float tw = __shfl_xor(u.w, m, 64);
                // left:  v' =  C*v + S*partner ; right: v' = C*v - S*partner
                v[r][c].x = C.x * u.x + S.x * tx;
                v[r][c].y = C.y * u.y + S.y * ty;
                v[r][c].z = C.z * u.z + S.z * tz;
                v[r][c].w = C.w * u.w + S.w * tw;
            }
        }
    }

    // ---- stage 8: pairs (c0,c1),(c2,c3); p = 256*(c>>1) + 4*lane + d ------
    {
        const float* cT = cosT + 8 * HALFD;
        const float* sT = sinT + 8 * HALFD;
        #pragma unroll
        for (int g = 0; g < 2; ++g) {
            const int p0 = 256 * g + 4 * lane;
            float4 C = *(const float4*)&cT[p0];
            float4 S = *(const float4*)&sT[p0];
            #pragma unroll
            for (int r = 0; r < R; ++r) {
                float4 L = v[r][2 * g], Rr = v[r][2 * g + 1];
                v[r][2 * g].x     = C.x * L.x + S.x * Rr.x;
                v[r][2 * g].y     = C.y * L.y + S.y * Rr.y;
                v[r][2 * g].z     = C.z * L.z + S.z * Rr.z;
                v[r][2 * g].w     = C.w * L.w + S.w * Rr.w;
                v[r][2 * g + 1].x = C.x * Rr.x - S.x * L.x;
                v[r][2 * g + 1].y = C.y * Rr.y - S.y * L.y;
                v[r][2 * g + 1].z = C.z * Rr.z - S.z * L.z;
                v[r][2 * g + 1].w = C.w * Rr.w - S.w * L.w;
            }
        }
    }

    // ---- stage 9: pairs (c0,c2),(c1,c3); p = 256*c + 4*lane + d (c=left) --
    {
        const float* cT = cosT + 9 * HALFD;
        const float* sT = sinT + 9 * HALFD;
        #pragma unroll
        for (int g = 0; g < 2; ++g) {
            const int p0 = 256 * g + 4 * lane;
            float4 C = *(const float4*)&cT[p0];
            float4 S = *(const float4*)&sT[p0];
            #pragma unroll
            for (int r = 0; r < R; ++r) {
                float4 L = v[r][g], Rr = v[r][g + 2];
                v[r][g].x     = C.x * L.x + S.x * Rr.x;
                v[r][g].y     = C.y * L.y + S.y * Rr.y;
                v[r][g].z     = C.z * L.z + S.z * Rr.z;
                v[r][g].w     = C.w * L.w + S.w * Rr.w;
                v[r][g + 2].x = C.x * Rr.x - S.x * L.x;
                v[r][g + 2].y = C.y * Rr.y - S.y * L.y;
                v[r][g + 2].z = C.z * Rr.z - S.z * L.z;
                v[r][g + 2].w = C.w * Rr.w - S.w * L.w;
            }
        }
    }

    // ---- store: coalesced -------------------------------------------------
    #pragma unroll
    for (int r = 0; r < R; ++r) {
        float4* op = ((float4*)(out + (size_t)(row0 + r) * DIM)) + lane;
        #pragma unroll
        for (int c = 0; c < 4; ++c)
            op[64 * c] = v[r][c];
    }
}

extern "C" void kernel_launch(void* const* d_in, const int* in_sizes, int n_in,
                              void* d_out, int out_size, void* d_ws, size_t ws_size,
                              hipStream_t stream) {
    const float* x   = (const float*)d_in[0];
    const float* ang = (const float*)d_in[1];
    float* out = (float*)d_out;

    const int nrows  = out_size / DIM;                 // 16384
    const int R = 2;
    const int nwaves  = (nrows + R - 1) / R;
    const int nblocks = (nwaves + 3) / 4;              // 4 waves / block

    if (ws_size >= (size_t)(2 * TABN * sizeof(float))) {
        float* tab = (float*)d_ws;
        bf_prep<<<(TABN + 255) / 256, 256, 0, stream>>>(ang, tab);
        bf_main<1><<<nblocks, 256, 0, stream>>>(x, ang, tab, out, nrows);
    } else {
        bf_main<0><<<nblocks, 256, 0, stream>>>(x, ang, nullptr, out, nrows);
    }
}